// Round 4
// baseline (913.129 us; speedup 1.0000x reference)
//
#include <hip/hip_runtime.h>
#include <hip/hip_bf16.h>

#define NN 32768
#define DEG 8
#define PW 552          // P table width (BigW cols); G row = 128 + PW = 680
#define GW 680          // combined per-node row width (floats)
#define GTP 684         // padded LDS width for G tile

typedef unsigned short u16;
typedef unsigned int u32;

__device__ __forceinline__ float bf2f(u32 lo16) { return __uint_as_float(lo16 << 16); }

// ---------------- dtype detection ----------------
__global__ void detect_kernel(const void* __restrict__ x, int* __restrict__ flagp) {
  if (threadIdx.x == 0) {
    const u16* u = (const u16*)x;
    int insane = 0;
    for (int i = 0; i < 128; ++i) {
      int e = (u[i] >> 7) & 0xff;
      if (e == 0 || e == 0xff || e < 0x70 || e > 0x8f) insane++;
    }
    *flagp = (insane >= 16) ? 0 : 1;   // 1 = bf16 inputs, 0 = f32 inputs
  }
}

// ---------------- input conversion ----------------
__global__ void cvt_kernel(const void* __restrict__ src, float* __restrict__ dst, int n,
                           const int* __restrict__ flagp) {
  const int f = *flagp;
  for (int i = blockIdx.x * 256 + threadIdx.x; i < n; i += gridDim.x * 256) {
    if (f) dst[i] = bf2f((u32)((const u16*)src)[i]);
    else   dst[i] = ((const float*)src)[i];
  }
}

// ---------------- derived small tables (one block per head) ----------------
__global__ __launch_bounds__(256) void derive_small_kernel(
    const float* __restrict__ qw, const float* __restrict__ qb,
    const float* __restrict__ ow, const float* __restrict__ ob,
    float* __restrict__ cq, float* __restrict__ ck, float* __restrict__ cvo,
    float* __restrict__ cc, float* __restrict__ bo_sum) {
  const int hd = blockIdx.x;                // 0..3
  const float* Wq = qw + (size_t)(hd*3 + 0) * 18769;
  const float* Wk = qw + (size_t)(hd*3 + 1) * 18769;
  const float* Wv = qw + (size_t)(hd*3 + 2) * 18769;
  const float* bq = qb + (hd*3 + 0) * 137;
  const float* bk = qb + (hd*3 + 1) * 137;
  const float* bv = qb + (hd*3 + 2) * 137;
  const float* Wo = ow + (size_t)hd * 18769;
  const int tid = threadIdx.x;

  for (int idx = tid; idx < 9*137; idx += 256) {
    int s = idx / 137, e = idx % 137;
    cq[hd*1233 + idx] = Wq[e*137 + 128 + s] + bq[e];
    ck[hd*1233 + idx] = Wk[e*137 + 128 + s] + bk[e];
  }
  __syncthreads();   // cc below reads cq/ck

  for (int idx = tid; idx < 9*128; idx += 256) {
    int s = idx >> 7, oi = idx & 127;
    float a = 0.f;
    for (int e = 0; e < 137; ++e) a += Wo[oi*137 + e] * (Wv[e*137 + 128 + s] + bv[e]);
    cvo[hd*1152 + idx] = a;
  }
  for (int idx = tid; idx < 81; idx += 256) {
    int i = idx / 9, j = idx % 9;
    float a = 0.f;
    for (int e = 0; e < 137; ++e) a += cq[hd*1233 + i*137 + e] * ck[hd*1233 + j*137 + e];
    cc[hd*81 + idx] = a;
  }
  if ((hd & 1) == 0) {
    int l = hd >> 1;
    for (int oi = tid; oi < 128; oi += 256)
      bo_sum[l*128 + oi] = ob[(l*2 + 0)*137 + oi] + ob[(l*2 + 1)*137 + oi];
  }
}

// ---------------- Mqk / Mvo (grid 64 x 4 heads, 1 thread per element) ----------------
__global__ __launch_bounds__(256) void derive_mm_kernel(
    const float* __restrict__ qw, const float* __restrict__ ow,
    float* __restrict__ Mqk, float* __restrict__ Mvo) {
  const int hd = blockIdx.y;
  const float* Wq = qw + (size_t)(hd*3 + 0) * 18769;
  const float* Wk = qw + (size_t)(hd*3 + 1) * 18769;
  const float* Wv = qw + (size_t)(hd*3 + 2) * 18769;
  const float* Wo = ow + (size_t)hd * 18769;
  const int idx = blockIdx.x * 256 + threadIdx.x;   // 0..16383
  const int row = idx >> 7, col = idx & 127;
  float sq = 0.f, so = 0.f;
  #pragma unroll 4
  for (int e = 0; e < 137; ++e) {
    sq += Wq[e*137 + row] * Wk[e*137 + col];     // Mqk[c][c']
    so += Wo[row*137 + e] * Wv[e*137 + col];     // Mvo[oi][c]
  }
  Mqk[hd*16384 + idx] = sq;
  Mvo[hd*16384 + idx] = so;
}

// BigW[l][k][col], 128 x PW per layer; BigW col c corresponds to G col 128+c
__global__ void bigw_kernel(const float* __restrict__ qw,
                            const float* __restrict__ Mqk, const float* __restrict__ Mvo,
                            const float* __restrict__ cq, const float* __restrict__ ck,
                            float* __restrict__ BigW) {
  const int idx = blockIdx.x * 256 + threadIdx.x;
  if (idx >= 2 * 128 * PW) return;
  const int l = idx / (128 * PW);
  const int r = idx % (128 * PW);
  const int k = r / PW, col = r % PW;
  float v = 0.f;
  if (col < 128)       v = Mqk[(l*2 + 0)*16384 + k*128 + col];
  else if (col < 256)  v = Mvo[(l*2 + 0)*16384 + (col - 128)*128 + k];
  else if (col < 384)  v = Mqk[(l*2 + 1)*16384 + k*128 + (col - 256)];
  else if (col < 512)  v = Mvo[(l*2 + 1)*16384 + (col - 384)*128 + k];
  else if (col < 530) {                       // qk_q: Hq_t . ck[t][j], linear in h
    int t = (col - 512) / 9, j = (col - 512) % 9;
    const float* Wq = qw + (size_t)((l*2 + t)*3 + 0) * 18769;
    const float* ckp = ck + (l*2 + t)*1233 + j*137;
    float a = 0.f;
    for (int e = 0; e < 137; ++e) a += Wq[e*137 + k] * ckp[e];
    v = a;
  } else if (col < 548) {                     // qk_k: cq[t][i] . Hk_t
    int t = (col - 530) / 9, i = (col - 530) % 9;
    const float* Wk_ = qw + (size_t)((l*2 + t)*3 + 1) * 18769;
    const float* cqp = cq + (l*2 + t)*1233 + i*137;
    float a = 0.f;
    for (int e = 0; e < 137; ++e) a += cqp[e] * Wk_[e*137 + k];
    v = a;
  }
  BigW[idx] = v;
}

// ---------------- 128x128-tile f32 GEMM: C = A(MxK) @ B(KxNC) ----------------
// M must be a multiple of 128. 256 threads, 8x8 micro-tile per thread.
__global__ __launch_bounds__(256) void gemm128_kernel(
    const float* __restrict__ A, const float* __restrict__ B,
    float* __restrict__ C,
    int M, int K, int NC, int lda, int ldb, int ldc) {
  __shared__ float As[16][128];   // k-major: fragment reads broadcast
  __shared__ float Bs[16][132];
  const int tid = threadIdx.x;
  const int row0 = blockIdx.y * 128, col0 = blockIdx.x * 128;
  const int tx = tid & 15, ty = tid >> 4;
  float acc[8][8] = {};
  const int nsteps = (K + 15) / 16;
  for (int step = 0; step < nsteps; ++step) {
    const int k0 = step * 16;
    {   // stage A: thread -> (row = tid>>1, k-octet = (tid&1)*8)
      const int ar = tid >> 1, aq = (tid & 1) * 8;
      const float* Ap = A + (size_t)(row0 + ar) * lda + k0 + aq;
      float av[8];
      if (k0 + 16 <= K) {
        const float4 v0 = *(const float4*)Ap;
        const float4 v1 = *(const float4*)(Ap + 4);
        av[0]=v0.x; av[1]=v0.y; av[2]=v0.z; av[3]=v0.w;
        av[4]=v1.x; av[5]=v1.y; av[6]=v1.z; av[7]=v1.w;
      } else {
        #pragma unroll
        for (int p = 0; p < 8; ++p) av[p] = (k0 + aq + p < K) ? Ap[p] : 0.f;
      }
      #pragma unroll
      for (int p = 0; p < 8; ++p) As[aq + p][ar] = av[p];
    }
    {   // stage B: thread -> (k = tid>>4, col-octet = (tid&15)*8)
      const int bk = tid >> 4, bc = (tid & 15) * 8;
      const int kg = k0 + bk;
      const float* Bp = B + (size_t)kg * ldb + col0 + bc;
      if (kg < K && col0 + bc + 8 <= NC) {
        *(float4*)&Bs[bk][bc]     = *(const float4*)Bp;
        *(float4*)&Bs[bk][bc + 4] = *(const float4*)(Bp + 4);
      } else {
        #pragma unroll
        for (int p = 0; p < 8; ++p)
          Bs[bk][bc + p] = (kg < K && col0 + bc + p < NC) ? Bp[p] : 0.f;
      }
    }
    __syncthreads();
    #pragma unroll
    for (int kk = 0; kk < 16; ++kk) {
      float a[8], b[8];
      *(float4*)&a[0] = *(const float4*)&As[kk][ty * 8];
      *(float4*)&a[4] = *(const float4*)&As[kk][ty * 8 + 4];
      *(float4*)&b[0] = *(const float4*)&Bs[kk][tx * 8];
      *(float4*)&b[4] = *(const float4*)&Bs[kk][tx * 8 + 4];
      #pragma unroll
      for (int i = 0; i < 8; ++i)
        #pragma unroll
        for (int j = 0; j < 8; ++j)
          acc[i][j] += a[i] * b[j];
    }
    __syncthreads();
  }
  #pragma unroll
  for (int i = 0; i < 8; ++i) {
    const int rr = row0 + ty * 8 + i;
    float* Cp = C + (size_t)rr * ldc + col0 + tx * 8;
    if (col0 + tx * 8 + 8 <= NC) {
      *(float4*)Cp       = make_float4(acc[i][0], acc[i][1], acc[i][2], acc[i][3]);
      *(float4*)(Cp + 4) = make_float4(acc[i][4], acc[i][5], acc[i][6], acc[i][7]);
    } else {
      #pragma unroll
      for (int j = 0; j < 8; ++j)
        if (col0 + tx * 8 + j < NC) Cp[j] = acc[i][j];
    }
  }
}

// ---------------- per-node fused attention: 2 nodes per block ----------------
// G row layout: [0..127]=h  [128..255]=hMq1  [256..383]=Go1  [384..511]=hMq2
//               [512..639]=Go2  [640..657]=qkq(t,j)  [658..675]=qkk(t,i)
__global__ __launch_bounds__(256) void attn_kernel(
    const int* __restrict__ src, const float* __restrict__ G,
    const float* __restrict__ cvo, const float* __restrict__ cc,
    const float* __restrict__ bo_sum, const float* __restrict__ b_layer,
    int layer, float* __restrict__ res) {
  __shared__ float T[2][9][GTP];
  __shared__ float As2[2][2][9][9];
  __shared__ int nbr[2][9];
  const int n0 = blockIdx.x * 2;
  const int tid = threadIdx.x;
  if (tid < 18) {
    const int nd = tid / 9, s = tid % 9;
    nbr[nd][s] = (s < 8) ? src[(n0 + nd) * DEG + s] : (n0 + nd);
  }
  __syncthreads();
  // gather: 2 nodes x 9 slots x 170 float4
  for (int it = tid; it < 2 * 9 * 170; it += 256) {
    const int nd = it / (9 * 170), r = it % (9 * 170);
    const int s = r / 170, w = r % 170;
    *(float4*)&T[nd][s][w * 4] = *(const float4*)(G + (size_t)nbr[nd][s] * GW + w * 4);
  }
  __syncthreads();
  // scores: 324 items = 2 nodes x 2 heads x 81 pairs
  for (int it = tid; it < 324; it += 256) {
    const int nd = it / 162, r = it % 162;
    const int t = r / 81, rr = r % 81, i = rr / 9, j = rr % 9;
    const float* hm = &T[nd][i][128 + t * 256];
    const float* hj = &T[nd][j][0];
    float s = 0.f;
    #pragma unroll 8
    for (int c = 0; c < 128; c += 4) {
      const float4 a = *(const float4*)&hm[c];
      const float4 b = *(const float4*)&hj[c];
      s += a.x * b.x + a.y * b.y + a.z * b.z + a.w * b.w;
    }
    s += T[nd][i][640 + t * 9 + j] + T[nd][j][658 + t * 9 + i]
       + cc[(layer * 2 + t) * 81 + rr];
    As2[nd][t][i][j] = s * 0.08543576577f;   // 1/sqrt(137)
  }
  __syncthreads();
  // softmax: 36 rows
  if (tid < 36) {
    const int nd = tid / 18, r = tid % 18, t = r / 9, i = r % 9;
    float* row = &As2[nd][t][i][0];
    float m = -3e38f;
    #pragma unroll
    for (int j = 0; j < 9; ++j) m = fmaxf(m, row[j]);
    float ex[9], ssum = 0.f;
    #pragma unroll
    for (int j = 0; j < 9; ++j) { ex[j] = expf(row[j] - m); ssum += ex[j]; }
    const float inv = 1.f / ssum;
    #pragma unroll
    for (int j = 0; j < 9; ++j) row[j] = ex[j] * inv;
  }
  __syncthreads();
  // PV + max: thread = (node, oi); all 9 query slots in-thread
  {
    const int nd = tid >> 7, oi = tid & 127;
    const float* cvo1 = cvo + (layer * 2 + 0) * 1152 + oi;
    const float* cvo2 = cvo + (layer * 2 + 1) * 1152 + oi;
    float vg1[9], vg2[9];
    #pragma unroll
    for (int j = 0; j < 9; ++j) {
      vg1[j] = T[nd][j][256 + oi] + cvo1[j * 128];
      vg2[j] = T[nd][j][512 + oi] + cvo2[j * 128];
    }
    float mx = -3e38f;
    #pragma unroll
    for (int i = 0; i < 9; ++i) {
      float y = T[nd][i][oi];
      #pragma unroll
      for (int j = 0; j < 9; ++j)
        y += As2[nd][0][i][j] * vg1[j] + As2[nd][1][i][j] * vg2[j];
      mx = fmaxf(mx, y);
    }
    res[(size_t)(n0 + nd) * 128 + oi] = mx + bo_sum[layer * 128 + oi] + b_layer[oi];
  }
}

// ---------------- pairnorm reductions ----------------
__global__ __launch_bounds__(256) void reduce_kernel(const float* __restrict__ res,
                                                     float* __restrict__ partial) {
  __shared__ float col2[128];
  __shared__ float sqs[256];
  const int b = blockIdx.x, tid = threadIdx.x;
  const int c = tid & 127, half = tid >> 7;
  float cs = 0.f, sq = 0.f;
  const int r0 = half * 64;
  for (int r = r0; r < r0 + 64; ++r) {
    const float v = res[((size_t)b * 128 + r) * 128 + c];
    cs += v; sq += v * v;
  }
  if (half) col2[c] = cs;
  sqs[tid] = sq;
  __syncthreads();
  if (!half) partial[b * 129 + c] = cs + col2[c];
  for (int s = 128; s >= 1; s >>= 1) {
    if (tid < s) sqs[tid] += sqs[tid + s];
    __syncthreads();
  }
  if (tid == 0) partial[b * 129 + 128] = sqs[0];
}

__global__ __launch_bounds__(128) void finalize_kernel(const float* __restrict__ partial,
                                                       float* __restrict__ stats) {
  __shared__ float musq[128];
  __shared__ float sqs[128];
  const int tid = threadIdx.x;
  float cs = 0.f;
  for (int b = 0; b < 256; ++b) cs += partial[b * 129 + tid];
  const float m = cs * (1.f / 32768.f);
  stats[tid] = m;
  musq[tid] = m * m;
  float sq = 0.f;
  for (int b = tid; b < 256; b += 128) sq += partial[b * 129 + 128];
  sqs[tid] = sq;
  __syncthreads();
  for (int s = 64; s >= 1; s >>= 1) {
    if (tid < s) { musq[tid] += musq[tid + s]; sqs[tid] += sqs[tid + s]; }
    __syncthreads();
  }
  if (tid == 0) {
    const float meansq = sqs[0] * (1.f / 32768.f);
    const float var = meansq - musq[0];
    stats[128] = 1.f / sqrtf(1e-6f + var);
  }
}

__global__ void norm_relu_kernel(const float* __restrict__ res, const float* __restrict__ stats,
                                 float* __restrict__ u) {
  const int idx = blockIdx.x * 256 + threadIdx.x;
  const int c = idx & 127;
  const float v = (res[idx] - stats[c]) * stats[128];
  u[idx] = fmaxf(v, 0.f);
}

__global__ void final_kernel(const float* __restrict__ res, const float* __restrict__ stats,
                             const float* __restrict__ xf, void* __restrict__ out,
                             const int* __restrict__ flagp) {
  const int idx = blockIdx.x * 256 + threadIdx.x;
  const int nrow = idx >> 7, c = idx & 127;
  float v = fmaxf((res[idx] - stats[c]) * stats[128], 0.f);
  v += xf[(size_t)nrow * 130 + c];
  if (c == 127 && (v > 1.f || v < -1.f)) v = 0.f;
  v *= 0.5f;
  if (*flagp) ((__hip_bfloat16*)out)[idx] = __float2bfloat16(v);
  else        ((float*)out)[idx] = v;
}

// ---------------- host ----------------
extern "C" void kernel_launch(void* const* d_in, const int* in_sizes, int n_in,
                              void* d_out, int out_size, void* d_ws, size_t ws_size,
                              hipStream_t stream) {
  (void)in_sizes; (void)n_in; (void)out_size; (void)ws_size;
  char* ws = (char*)d_ws;
  size_t off = 0;
  auto alloc = [&](size_t bytes) -> char* {
    char* p = ws + off;
    off += (bytes + 255) & ~(size_t)255;
    return p;
  };
  int*   flagp = (int*)  alloc(4);
  float* xf    = (float*)alloc((size_t)NN * 130 * 4);
  float* W1f   = (float*)alloc(130 * 128 * 4);
  float* b1f   = (float*)alloc(128 * 4);
  float* W2f   = (float*)alloc(128 * 128 * 4);
  float* b2f   = (float*)alloc(128 * 4);
  float* qwf   = (float*)alloc((size_t)225228 * 4);
  float* qbf   = (float*)alloc(1644 * 4);
  float* owf   = (float*)alloc((size_t)75076 * 4);
  float* obf   = (float*)alloc(548 * 4);
  float* Mqk   = (float*)alloc((size_t)4 * 16384 * 4);
  float* Mvo   = (float*)alloc((size_t)4 * 16384 * 4);
  float* cq    = (float*)alloc((size_t)4 * 1233 * 4);
  float* ck    = (float*)alloc((size_t)4 * 1233 * 4);
  float* cvo   = (float*)alloc((size_t)4 * 1152 * 4);
  float* cc    = (float*)alloc((size_t)4 * 81 * 4);
  float* boS   = (float*)alloc((size_t)2 * 128 * 4);
  float* BigW  = (float*)alloc((size_t)2 * 128 * PW * 4);
  float* G     = (float*)alloc((size_t)NN * GW * 4);
  float* res   = (float*)alloc((size_t)NN * 128 * 4);
  float* ubuf  = (float*)alloc((size_t)NN * 128 * 4);
  float* part  = (float*)alloc((size_t)256 * 129 * 4);
  float* st0   = (float*)alloc(132 * 4);
  float* st1   = (float*)alloc(132 * 4);

  const int* edge = (const int*)d_in[1];   // row 0 = src

  detect_kernel<<<1, 64, 0, stream>>>(d_in[0], flagp);

  struct CvtDesc { const void* src; float* dst; int n; };
  const CvtDesc cv[9] = {
    { d_in[0], xf,  NN * 130 },
    { d_in[2], W1f, 130 * 128 },
    { d_in[3], b1f, 128 },
    { d_in[4], W2f, 128 * 128 },
    { d_in[5], b2f, 128 },
    { d_in[6], qwf, 225228 },
    { d_in[7], qbf, 1644 },
    { d_in[8], owf, 75076 },
    { d_in[9], obf, 548 },
  };
  for (int i = 0; i < 9; ++i) {
    int blocks = (cv[i].n + 255) / 256;
    if (blocks > 4096) blocks = 4096;
    cvt_kernel<<<blocks, 256, 0, stream>>>(cv[i].src, cv[i].dst, cv[i].n, flagp);
  }

  derive_small_kernel<<<4, 256, 0, stream>>>(qwf, qbf, owf, obf, cq, ck, cvo, cc, boS);
  derive_mm_kernel<<<dim3(64, 4), 256, 0, stream>>>(qwf, owf, Mqk, Mvo);
  bigw_kernel<<<(2 * 128 * PW + 255) / 256, 256, 0, stream>>>(qwf, Mqk, Mvo, cq, ck, BigW);

  for (int l = 0; l < 2; ++l) {
    const float* act = l ? ubuf : xf;
    const int K = l ? 128 : 130;
    const float* W = l ? W2f : W1f;
    // h = act @ W  -> G cols 0..127
    gemm128_kernel<<<dim3(1, NN / 128), 256, 0, stream>>>(
        act, W, G, NN, K, 128, K, 128, GW);
    // P = h @ BigW_l -> G cols 128..679 (reads G cols <128, writes cols >=128: disjoint)
    gemm128_kernel<<<dim3((PW + 127) / 128, NN / 128), 256, 0, stream>>>(
        G, BigW + (size_t)l * 128 * PW, G + 128,
        NN, 128, PW, GW, PW, GW);
    // fused per-node attention + max + bias (2 nodes per block)
    attn_kernel<<<NN / 2, 256, 0, stream>>>(edge, G, cvo, cc, boS,
                                            l ? b2f : b1f, l, res);
    // pairnorm stats
    reduce_kernel<<<256, 256, 0, stream>>>(res, part);
    finalize_kernel<<<1, 128, 0, stream>>>(part, l ? st1 : st0);
    if (l == 0) {
      norm_relu_kernel<<<NN * 128 / 256, 256, 0, stream>>>(res, st0, ubuf);
    } else {
      final_kernel<<<NN * 128 / 256, 256, 0, stream>>>(res, st1, xf, d_out, flagp);
    }
  }
}

// Round 5
// 743.112 us; speedup vs baseline: 1.2288x; 1.2288x over previous
//
#include <hip/hip_runtime.h>
#include <hip/hip_bf16.h>

#define NN 32768
#define DEG 8
#define PW 548          // BigW cols: hMq1(128) hMq2(128) qk(36) Go1(128) Go2(128)
#define GW 676          // G row: h(128) | hMq1 | hMq2 | qk(36) | Go1 | Go2
#define SFW 420         // score-feeding prefix width (floats) = 105 float4
#define TP 428          // padded LDS tile width

typedef unsigned short u16;
typedef unsigned int u32;

__device__ __forceinline__ float bf2f(u32 lo16) { return __uint_as_float(lo16 << 16); }

// ---------------- dtype detection ----------------
__global__ void detect_kernel(const void* __restrict__ x, int* __restrict__ flagp) {
  if (threadIdx.x == 0) {
    const u16* u = (const u16*)x;
    int insane = 0;
    for (int i = 0; i < 128; ++i) {
      int e = (u[i] >> 7) & 0xff;
      if (e == 0 || e == 0xff || e < 0x70 || e > 0x8f) insane++;
    }
    *flagp = (insane >= 16) ? 0 : 1;   // 1 = bf16 inputs, 0 = f32 inputs
  }
}

// ---------------- input conversion ----------------
__global__ void cvt_kernel(const void* __restrict__ src, float* __restrict__ dst, int n,
                           const int* __restrict__ flagp) {
  const int f = *flagp;
  for (int i = blockIdx.x * 256 + threadIdx.x; i < n; i += gridDim.x * 256) {
    if (f) dst[i] = bf2f((u32)((const u16*)src)[i]);
    else   dst[i] = ((const float*)src)[i];
  }
}

// ---------------- derived small tables (one block per head) ----------------
__global__ __launch_bounds__(256) void derive_small_kernel(
    const float* __restrict__ qw, const float* __restrict__ qb,
    const float* __restrict__ ow, const float* __restrict__ ob,
    float* __restrict__ cq, float* __restrict__ ck, float* __restrict__ cvo,
    float* __restrict__ cc, float* __restrict__ bo_sum) {
  const int hd = blockIdx.x;                // 0..3
  const float* Wq = qw + (size_t)(hd*3 + 0) * 18769;
  const float* Wk = qw + (size_t)(hd*3 + 1) * 18769;
  const float* Wv = qw + (size_t)(hd*3 + 2) * 18769;
  const float* bq = qb + (hd*3 + 0) * 137;
  const float* bk = qb + (hd*3 + 1) * 137;
  const float* bv = qb + (hd*3 + 2) * 137;
  const float* Wo = ow + (size_t)hd * 18769;
  const int tid = threadIdx.x;

  for (int idx = tid; idx < 9*137; idx += 256) {
    int s = idx / 137, e = idx % 137;
    cq[hd*1233 + idx] = Wq[e*137 + 128 + s] + bq[e];
    ck[hd*1233 + idx] = Wk[e*137 + 128 + s] + bk[e];
  }
  __syncthreads();   // cc below reads cq/ck

  for (int idx = tid; idx < 9*128; idx += 256) {
    int s = idx >> 7, oi = idx & 127;
    float a = 0.f;
    for (int e = 0; e < 137; ++e) a += Wo[oi*137 + e] * (Wv[e*137 + 128 + s] + bv[e]);
    cvo[hd*1152 + idx] = a;
  }
  for (int idx = tid; idx < 81; idx += 256) {
    int i = idx / 9, j = idx % 9;
    float a = 0.f;
    for (int e = 0; e < 137; ++e) a += cq[hd*1233 + i*137 + e] * ck[hd*1233 + j*137 + e];
    cc[hd*81 + idx] = a;
  }
  if ((hd & 1) == 0) {
    int l = hd >> 1;
    for (int oi = tid; oi < 128; oi += 256)
      bo_sum[l*128 + oi] = ob[(l*2 + 0)*137 + oi] + ob[(l*2 + 1)*137 + oi];
  }
}

// ---------------- Mqk / Mvo (grid 64 x 4 heads, 1 thread per element) ----------------
__global__ __launch_bounds__(256) void derive_mm_kernel(
    const float* __restrict__ qw, const float* __restrict__ ow,
    float* __restrict__ Mqk, float* __restrict__ Mvo) {
  const int hd = blockIdx.y;
  const float* Wq = qw + (size_t)(hd*3 + 0) * 18769;
  const float* Wk = qw + (size_t)(hd*3 + 1) * 18769;
  const float* Wv = qw + (size_t)(hd*3 + 2) * 18769;
  const float* Wo = ow + (size_t)hd * 18769;
  const int idx = blockIdx.x * 256 + threadIdx.x;   // 0..16383
  const int row = idx >> 7, col = idx & 127;
  float sq = 0.f, so = 0.f;
  #pragma unroll 4
  for (int e = 0; e < 137; ++e) {
    sq += Wq[e*137 + row] * Wk[e*137 + col];     // Mqk[c][c']
    so += Wo[row*137 + e] * Wv[e*137 + col];     // Mvo[oi][c]
  }
  Mqk[hd*16384 + idx] = sq;
  Mvo[hd*16384 + idx] = so;
}

// BigW[l][k][col], 128 x PW per layer; BigW col c corresponds to G col 128+c
// layout: [0..127]=Mqk1  [128..255]=Mqk2  [256..291]=qk  [292..419]=Mvo1  [420..547]=Mvo2
__global__ void bigw_kernel(const float* __restrict__ qw,
                            const float* __restrict__ Mqk, const float* __restrict__ Mvo,
                            const float* __restrict__ cq, const float* __restrict__ ck,
                            float* __restrict__ BigW) {
  const int idx = blockIdx.x * 256 + threadIdx.x;
  if (idx >= 2 * 128 * PW) return;
  const int l = idx / (128 * PW);
  const int r = idx % (128 * PW);
  const int k = r / PW, col = r % PW;
  float v = 0.f;
  if (col < 128)       v = Mqk[(l*2 + 0)*16384 + k*128 + col];
  else if (col < 256)  v = Mqk[(l*2 + 1)*16384 + k*128 + (col - 128)];
  else if (col < 274) {                       // qk_q: Hq_t . ck[t][j], linear in h
    int q = col - 256, t = q / 9, j = q % 9;
    const float* Wq = qw + (size_t)((l*2 + t)*3 + 0) * 18769;
    const float* ckp = ck + (l*2 + t)*1233 + j*137;
    float a = 0.f;
    for (int e = 0; e < 137; ++e) a += Wq[e*137 + k] * ckp[e];
    v = a;
  } else if (col < 292) {                     // qk_k: cq[t][i] . Hk_t
    int q = col - 274, t = q / 9, i = q % 9;
    const float* Wk_ = qw + (size_t)((l*2 + t)*3 + 1) * 18769;
    const float* cqp = cq + (l*2 + t)*1233 + i*137;
    float a = 0.f;
    for (int e = 0; e < 137; ++e) a += cqp[e] * Wk_[e*137 + k];
    v = a;
  }
  else if (col < 420)  v = Mvo[(l*2 + 0)*16384 + (col - 292)*128 + k];
  else                 v = Mvo[(l*2 + 1)*16384 + (col - 420)*128 + k];
  BigW[idx] = v;
}

// ---------------- 128x128-tile f32 GEMM: C = A(MxK) @ B(KxNC) ----------------
// M must be a multiple of 128. 256 threads, 8x8 micro-tile per thread.
__global__ __launch_bounds__(256) void gemm128_kernel(
    const float* __restrict__ A, const float* __restrict__ B,
    float* __restrict__ C,
    int M, int K, int NC, int lda, int ldb, int ldc) {
  __shared__ float As[16][128];   // k-major: fragment reads broadcast
  __shared__ float Bs[16][132];
  const int tid = threadIdx.x;
  const int row0 = blockIdx.y * 128, col0 = blockIdx.x * 128;
  const int tx = tid & 15, ty = tid >> 4;
  float acc[8][8] = {};
  const int nsteps = (K + 15) / 16;
  for (int step = 0; step < nsteps; ++step) {
    const int k0 = step * 16;
    {   // stage A: thread -> (row = tid>>1, k-octet = (tid&1)*8)
      const int ar = tid >> 1, aq = (tid & 1) * 8;
      const float* Ap = A + (size_t)(row0 + ar) * lda + k0 + aq;
      float av[8];
      if (k0 + 16 <= K) {
        const float4 v0 = *(const float4*)Ap;
        const float4 v1 = *(const float4*)(Ap + 4);
        av[0]=v0.x; av[1]=v0.y; av[2]=v0.z; av[3]=v0.w;
        av[4]=v1.x; av[5]=v1.y; av[6]=v1.z; av[7]=v1.w;
      } else {
        #pragma unroll
        for (int p = 0; p < 8; ++p) av[p] = (k0 + aq + p < K) ? Ap[p] : 0.f;
      }
      #pragma unroll
      for (int p = 0; p < 8; ++p) As[aq + p][ar] = av[p];
    }
    {   // stage B: thread -> (k = tid>>4, col-octet = (tid&15)*8)
      const int bk = tid >> 4, bc = (tid & 15) * 8;
      const int kg = k0 + bk;
      const float* Bp = B + (size_t)kg * ldb + col0 + bc;
      if (kg < K && col0 + bc + 8 <= NC) {
        *(float4*)&Bs[bk][bc]     = *(const float4*)Bp;
        *(float4*)&Bs[bk][bc + 4] = *(const float4*)(Bp + 4);
      } else {
        #pragma unroll
        for (int p = 0; p < 8; ++p)
          Bs[bk][bc + p] = (kg < K && col0 + bc + p < NC) ? Bp[p] : 0.f;
      }
    }
    __syncthreads();
    #pragma unroll
    for (int kk = 0; kk < 16; ++kk) {
      float a[8], b[8];
      *(float4*)&a[0] = *(const float4*)&As[kk][ty * 8];
      *(float4*)&a[4] = *(const float4*)&As[kk][ty * 8 + 4];
      *(float4*)&b[0] = *(const float4*)&Bs[kk][tx * 8];
      *(float4*)&b[4] = *(const float4*)&Bs[kk][tx * 8 + 4];
      #pragma unroll
      for (int i = 0; i < 8; ++i)
        #pragma unroll
        for (int j = 0; j < 8; ++j)
          acc[i][j] += a[i] * b[j];
    }
    __syncthreads();
  }
  #pragma unroll
  for (int i = 0; i < 8; ++i) {
    const int rr = row0 + ty * 8 + i;
    float* Cp = C + (size_t)rr * ldc + col0 + tx * 8;
    if (col0 + tx * 8 + 8 <= NC) {
      *(float4*)Cp       = make_float4(acc[i][0], acc[i][1], acc[i][2], acc[i][3]);
      *(float4*)(Cp + 4) = make_float4(acc[i][4], acc[i][5], acc[i][6], acc[i][7]);
    } else {
      #pragma unroll
      for (int j = 0; j < 8; ++j)
        if (col0 + tx * 8 + j < NC) Cp[j] = acc[i][j];
    }
  }
}

// ---------------- per-node fused attention (1 node/block, minimal LDS) ----------------
// G row: [0..127]=h  [128..255]=hMq1  [256..383]=hMq2  [384..401]=qkq(t,j)
//        [402..419]=qkk(t,i)  [420..547]=Go1  [548..675]=Go2
__global__ __launch_bounds__(256) void attn_kernel(
    const int* __restrict__ src, const float* __restrict__ G,
    const float* __restrict__ cvo, const float* __restrict__ cc,
    const float* __restrict__ bo_sum, const float* __restrict__ b_layer,
    int layer, float* __restrict__ res) {
  __shared__ float T[9][TP];          // score-feeding prefix of each slot
  __shared__ float As[2][9][9];
  __shared__ float ymax[2][128];
  __shared__ int nbr[9];
  const int n = blockIdx.x;
  const int tid = threadIdx.x;
  if (tid < 9) nbr[tid] = (tid < 8) ? src[n * DEG + tid] : n;
  __syncthreads();
  // gather: 9 slots x 105 float4 (cols 0..419)
  for (int it = tid; it < 9 * 105; it += 256) {
    const int s = it / 105, w = it % 105;
    *(float4*)&T[s][w * 4] = *(const float4*)(G + (size_t)nbr[s] * GW + w * 4);
  }
  __syncthreads();
  // scores: 162 = 2 heads x 81 pairs
  if (tid < 162) {
    const int t = tid / 81, r = tid % 81, i = r / 9, j = r % 9;
    const float* hm = &T[i][128 + t * 128];
    const float* hj = &T[j][0];
    float s = 0.f;
    #pragma unroll 8
    for (int c = 0; c < 128; c += 4) {
      const float4 a = *(const float4*)&hm[c];
      const float4 b = *(const float4*)&hj[c];
      s += a.x * b.x + a.y * b.y + a.z * b.z + a.w * b.w;
    }
    s += T[i][384 + t*9 + j] + T[j][402 + t*9 + i] + cc[(layer*2 + t)*81 + r];
    As[t][i][j] = s * 0.08543576577f;   // 1/sqrt(137)
  }
  __syncthreads();
  if (tid < 18) {
    const int t = tid / 9, i = tid % 9;
    float* row = &As[t][i][0];
    float m = -3e38f;
    #pragma unroll
    for (int j = 0; j < 9; ++j) m = fmaxf(m, row[j]);
    float ex[9], ssum = 0.f;
    #pragma unroll
    for (int j = 0; j < 9; ++j) { ex[j] = expf(row[j] - m); ssum += ex[j]; }
    const float inv = 1.f / ssum;
    #pragma unroll
    for (int j = 0; j < 9; ++j) row[j] = ex[j] * inv;
  }
  __syncthreads();
  // PV + max: Go read directly from global (coalesced column chunks)
  {
    const int oi = tid & 127, half = tid >> 7;
    const float* cvo1 = cvo + (layer * 2 + 0) * 1152 + oi;
    const float* cvo2 = cvo + (layer * 2 + 1) * 1152 + oi;
    float vg1[9], vg2[9];
    #pragma unroll
    for (int j = 0; j < 9; ++j) {
      const float* gr = G + (size_t)nbr[j] * GW + oi;
      vg1[j] = gr[420] + cvo1[j * 128];
      vg2[j] = gr[548] + cvo2[j * 128];
    }
    float mx = -3e38f;
    const int i0 = half ? 5 : 0, i1 = half ? 9 : 5;
    for (int i = i0; i < i1; ++i) {
      float y = T[i][oi];
      #pragma unroll
      for (int j = 0; j < 9; ++j)
        y += As[0][i][j] * vg1[j] + As[1][i][j] * vg2[j];
      mx = fmaxf(mx, y);
    }
    ymax[half][oi] = mx;
  }
  __syncthreads();
  if (tid < 128) {
    const float v = fmaxf(ymax[0][tid], ymax[1][tid]) + bo_sum[layer*128 + tid] + b_layer[tid];
    res[(size_t)n * 128 + tid] = v;
  }
}

// ---------------- pairnorm reductions ----------------
__global__ __launch_bounds__(256) void reduce_kernel(const float* __restrict__ res,
                                                     float* __restrict__ partial) {
  __shared__ float col2[128];
  __shared__ float sqs[256];
  const int b = blockIdx.x, tid = threadIdx.x;
  const int c = tid & 127, half = tid >> 7;
  float cs = 0.f, sq = 0.f;
  const int r0 = half * 64;
  for (int r = r0; r < r0 + 64; ++r) {
    const float v = res[((size_t)b * 128 + r) * 128 + c];
    cs += v; sq += v * v;
  }
  if (half) col2[c] = cs;
  sqs[tid] = sq;
  __syncthreads();
  if (!half) partial[b * 129 + c] = cs + col2[c];
  for (int s = 128; s >= 1; s >>= 1) {
    if (tid < s) sqs[tid] += sqs[tid + s];
    __syncthreads();
  }
  if (tid == 0) partial[b * 129 + 128] = sqs[0];
}

__global__ __launch_bounds__(128) void finalize_kernel(const float* __restrict__ partial,
                                                       float* __restrict__ stats) {
  __shared__ float musq[128];
  __shared__ float sqs[128];
  const int tid = threadIdx.x;
  float cs = 0.f;
  for (int b = 0; b < 256; ++b) cs += partial[b * 129 + tid];
  const float m = cs * (1.f / 32768.f);
  stats[tid] = m;
  musq[tid] = m * m;
  float sq = 0.f;
  for (int b = tid; b < 256; b += 128) sq += partial[b * 129 + 128];
  sqs[tid] = sq;
  __syncthreads();
  for (int s = 64; s >= 1; s >>= 1) {
    if (tid < s) { musq[tid] += musq[tid + s]; sqs[tid] += sqs[tid + s]; }
    __syncthreads();
  }
  if (tid == 0) {
    const float meansq = sqs[0] * (1.f / 32768.f);
    const float var = meansq - musq[0];
    stats[128] = 1.f / sqrtf(1e-6f + var);
  }
}

__global__ void norm_relu_kernel(const float* __restrict__ res, const float* __restrict__ stats,
                                 float* __restrict__ u) {
  const int idx = blockIdx.x * 256 + threadIdx.x;
  const int c = idx & 127;
  const float v = (res[idx] - stats[c]) * stats[128];
  u[idx] = fmaxf(v, 0.f);
}

__global__ void final_kernel(const float* __restrict__ res, const float* __restrict__ stats,
                             const float* __restrict__ xf, void* __restrict__ out,
                             const int* __restrict__ flagp) {
  const int idx = blockIdx.x * 256 + threadIdx.x;
  const int nrow = idx >> 7, c = idx & 127;
  float v = fmaxf((res[idx] - stats[c]) * stats[128], 0.f);
  v += xf[(size_t)nrow * 130 + c];
  if (c == 127 && (v > 1.f || v < -1.f)) v = 0.f;
  v *= 0.5f;
  if (*flagp) ((__hip_bfloat16*)out)[idx] = __float2bfloat16(v);
  else        ((float*)out)[idx] = v;
}

// ---------------- host ----------------
extern "C" void kernel_launch(void* const* d_in, const int* in_sizes, int n_in,
                              void* d_out, int out_size, void* d_ws, size_t ws_size,
                              hipStream_t stream) {
  (void)in_sizes; (void)n_in; (void)out_size; (void)ws_size;
  char* ws = (char*)d_ws;
  size_t off = 0;
  auto alloc = [&](size_t bytes) -> char* {
    char* p = ws + off;
    off += (bytes + 255) & ~(size_t)255;
    return p;
  };
  int*   flagp = (int*)  alloc(4);
  float* xf    = (float*)alloc((size_t)NN * 130 * 4);
  float* W1f   = (float*)alloc(130 * 128 * 4);
  float* b1f   = (float*)alloc(128 * 4);
  float* W2f   = (float*)alloc(128 * 128 * 4);
  float* b2f   = (float*)alloc(128 * 4);
  float* qwf   = (float*)alloc((size_t)225228 * 4);
  float* qbf   = (float*)alloc(1644 * 4);
  float* owf   = (float*)alloc((size_t)75076 * 4);
  float* obf   = (float*)alloc(548 * 4);
  float* Mqk   = (float*)alloc((size_t)4 * 16384 * 4);
  float* Mvo   = (float*)alloc((size_t)4 * 16384 * 4);
  float* cq    = (float*)alloc((size_t)4 * 1233 * 4);
  float* ck    = (float*)alloc((size_t)4 * 1233 * 4);
  float* cvo   = (float*)alloc((size_t)4 * 1152 * 4);
  float* cc    = (float*)alloc((size_t)4 * 81 * 4);
  float* boS   = (float*)alloc((size_t)2 * 128 * 4);
  float* BigW  = (float*)alloc((size_t)2 * 128 * PW * 4);
  float* G     = (float*)alloc((size_t)NN * GW * 4);
  float* res   = (float*)alloc((size_t)NN * 128 * 4);
  float* ubuf  = (float*)alloc((size_t)NN * 128 * 4);
  float* part  = (float*)alloc((size_t)256 * 129 * 4);
  float* st0   = (float*)alloc(132 * 4);
  float* st1   = (float*)alloc(132 * 4);

  const int* edge = (const int*)d_in[1];   // row 0 = src

  detect_kernel<<<1, 64, 0, stream>>>(d_in[0], flagp);

  struct CvtDesc { const void* src; float* dst; int n; };
  const CvtDesc cv[9] = {
    { d_in[0], xf,  NN * 130 },
    { d_in[2], W1f, 130 * 128 },
    { d_in[3], b1f, 128 },
    { d_in[4], W2f, 128 * 128 },
    { d_in[5], b2f, 128 },
    { d_in[6], qwf, 225228 },
    { d_in[7], qbf, 1644 },
    { d_in[8], owf, 75076 },
    { d_in[9], obf, 548 },
  };
  for (int i = 0; i < 9; ++i) {
    int blocks = (cv[i].n + 255) / 256;
    if (blocks > 4096) blocks = 4096;
    cvt_kernel<<<blocks, 256, 0, stream>>>(cv[i].src, cv[i].dst, cv[i].n, flagp);
  }

  derive_small_kernel<<<4, 256, 0, stream>>>(qwf, qbf, owf, obf, cq, ck, cvo, cc, boS);
  derive_mm_kernel<<<dim3(64, 4), 256, 0, stream>>>(qwf, owf, Mqk, Mvo);
  bigw_kernel<<<(2 * 128 * PW + 255) / 256, 256, 0, stream>>>(qwf, Mqk, Mvo, cq, ck, BigW);

  for (int l = 0; l < 2; ++l) {
    const float* act = l ? ubuf : xf;
    const int K = l ? 128 : 130;
    const float* W = l ? W2f : W1f;
    // h = act @ W  -> G cols 0..127
    gemm128_kernel<<<dim3(1, NN / 128), 256, 0, stream>>>(
        act, W, G, NN, K, 128, K, 128, GW);
    // P = h @ BigW_l -> G cols 128..675 (reads cols <128, writes cols >=128: disjoint)
    gemm128_kernel<<<dim3((PW + 127) / 128, NN / 128), 256, 0, stream>>>(
        G, BigW + (size_t)l * 128 * PW, G + 128,
        NN, 128, PW, GW, PW, GW);
    // fused per-node attention + max + bias
    attn_kernel<<<NN, 256, 0, stream>>>(edge, G, cvo, cc, boS,
                                        l ? b2f : b1f, l, res);
    // pairnorm stats
    reduce_kernel<<<256, 256, 0, stream>>>(res, part);
    finalize_kernel<<<1, 128, 0, stream>>>(part, l ? st1 : st0);
    if (l == 0) {
      norm_relu_kernel<<<NN * 128 / 256, 256, 0, stream>>>(res, st0, ubuf);
    } else {
      final_kernel<<<NN * 128 / 256, 256, 0, stream>>>(res, st1, xf, d_out, flagp);
    }
  }
}